// Round 13
// baseline (211.562 us; speedup 1.0000x reference)
//
#include <hip/hip_runtime.h>
#include <cstdint>

#define NXX 512
#define NYY 512
#define NCH 32
#define NB  8
#define NU  257              // NYY/2+1
#define IMG_CPLX (NU*NXX)    // 131584 complex per image, [u][i] i-contiguous
#define PIX (NXX*NYY)        // 262144
#define BCAP 768             // bin capacity (mean 195, 40 sigma headroom)

__device__ __forceinline__ uint32_t f2bf(float f){
  uint32_t u = __float_as_uint(f);
  return (u + 0x7FFFu + ((u >> 16) & 1u)) >> 16;   // RNE
}
__device__ __forceinline__ float bf2f(uint32_t h){ return __uint_as_float(h << 16); }
__device__ __forceinline__ uint32_t packbf(float re, float im){ return f2bf(re) | (f2bf(im) << 16); }

#define WAIT_LGKM() asm volatile("s_waitcnt lgkmcnt(0)" ::: "memory")

__device__ __forceinline__ void cmul(float& zr, float& zi, float wr, float wi){
  float r = zr*wr - zi*wi;
  zi = zr*wi + zi*wr;
  zr = r;
}

// 8-point DFT, DIR=-1 forward (e^{-i}), DIR=+1 inverse (unnormalized)
template<int DIR>
__device__ __forceinline__ void bfly8(float* xr, float* xi){
  const float S = 0.70710678118654752440f;
  float er0=xr[0]+xr[4], ei0=xi[0]+xi[4];
  float er1=xr[1]+xr[5], ei1=xi[1]+xi[5];
  float er2=xr[2]+xr[6], ei2=xi[2]+xi[6];
  float er3=xr[3]+xr[7], ei3=xi[3]+xi[7];
  float or0=xr[0]-xr[4], oi0=xi[0]-xi[4];
  float or1=xr[1]-xr[5], oi1=xi[1]-xi[5];
  float or2=xr[2]-xr[6], oi2=xi[2]-xi[6];
  float or3=xr[3]-xr[7], oi3=xi[3]-xi[7];
  float p0r=er0+er2, p0i=ei0+ei2;
  float p1r=er0-er2, p1i=ei0-ei2;
  float q0r=er1+er3, q0i=ei1+ei3;
  float q1r=er1-er3, q1i=ei1-ei3;
  float w4r, w4i;
  if (DIR<0){ w4r=q1i; w4i=-q1r; } else { w4r=-q1i; w4i=q1r; }
  xr[0]=p0r+q0r; xi[0]=p0i+q0i;
  xr[4]=p0r-q0r; xi[4]=p0i-q0i;
  xr[2]=p1r+w4r; xi[2]=p1i+w4i;
  xr[6]=p1r-w4r; xi[6]=p1i-w4i;
  float f1r,f1i,f2r,f2i,f3r,f3i;
  if (DIR<0){
    f1r=S*(or1+oi1); f1i=S*(oi1-or1);
    f2r=oi2;         f2i=-or2;
    f3r=S*(oi3-or3); f3i=-S*(or3+oi3);
  } else {
    f1r=S*(or1-oi1);  f1i=S*(or1+oi1);
    f2r=-oi2;         f2i=or2;
    f3r=-S*(or3+oi3); f3i=S*(or3-oi3);
  }
  float g0r=or0+f2r, g0i=oi0+f2i;
  float g1r=or0-f2r, g1i=oi0-f2i;
  float h0r=f1r+f3r, h0i=f1i+f3i;
  float h1r=f1r-f3r, h1i=f1i-f3i;
  float v4r, v4i;
  if (DIR<0){ v4r=h1i; v4i=-h1r; } else { v4r=-h1i; v4i=h1r; }
  xr[1]=g0r+h0r; xi[1]=g0i+h0i;
  xr[5]=g0r-h0r; xi[5]=g0i-h0i;
  xr[3]=g1r+v4r; xi[3]=g1i+v4i;
  xr[7]=g1r-v4r; xi[7]=g1i-v4i;
}

__device__ __forceinline__ void make_tw(int t, float* t1r, float* t1i, float* t2r, float* t2i){
  const float TP = 6.283185307179586476925f;
  float s, c;
  sincosf(-TP * (float)t * (1.0f/512.0f), &s, &c);
  t1r[0]=1.0f; t1i[0]=0.0f;
  #pragma unroll
  for (int k=1;k<8;k++){ t1r[k]=t1r[k-1]*c - t1i[k-1]*s; t1i[k]=t1r[k-1]*s + t1i[k-1]*c; }
  sincosf(-TP * (float)(t>>3) * (1.0f/64.0f), &s, &c);
  t2r[0]=1.0f; t2i[0]=0.0f;
  #pragma unroll
  for (int k=1;k<8;k++){ t2r[k]=t2r[k-1]*c - t2i[k-1]*s; t2i[k]=t2r[k-1]*s + t2i[k-1]*c; }
}

// 512-pt complex Stockham radix-8, one wave, 8 complex/lane.
// Input : a[j] = x[t + 64j].  Output: a[k] = X[t + 64k] (natural order).
template<int DIR>
__device__ __forceinline__ void fft512(float* ar, float* ai, float* sre, float* sim, int t,
    const float* t1r, const float* t1i, const float* t2r, const float* t2i){
  bfly8<DIR>(ar, ai);
  #pragma unroll
  for (int k=1;k<8;k++){ cmul(ar[k], ai[k], t1r[k], (DIR<0)? t1i[k] : -t1i[k]); }
  #pragma unroll
  for (int k=0;k<8;k++){ int d = 8*t + k; d += (d>>5); sre[d]=ar[k]; sim[d]=ai[k]; }
  WAIT_LGKM();
  #pragma unroll
  for (int j=0;j<8;j++){ int s2 = t + (j<<6); s2 += (s2>>5); ar[j]=sre[s2]; ai[j]=sim[s2]; }
  WAIT_LGKM();
  bfly8<DIR>(ar, ai);
  #pragma unroll
  for (int k=1;k<8;k++){ cmul(ar[k], ai[k], t2r[k], (DIR<0)? t2i[k] : -t2i[k]); }
  #pragma unroll
  for (int k=0;k<8;k++){ int d = (t&7) + ((t>>3)<<6) + (k<<3); d += (d>>5); sre[d]=ar[k]; sim[d]=ai[k]; }
  WAIT_LGKM();
  #pragma unroll
  for (int j=0;j<8;j++){ int s2 = t + (j<<6); s2 += (s2>>5); ar[j]=sre[s2]; ai[j]=sim[s2]; }
  WAIT_LGKM();
  bfly8<DIR>(ar, ai);
}

// bin the sparse PSF entries by (channel, 32-row block): 512 bins.
// entry = ((lrow<<9)|col)<<16 | bf16(relu(v))
__global__ void k_bin(const float* __restrict__ vk, const int* __restrict__ loc,
                      uint32_t* __restrict__ cnt, uint32_t* __restrict__ ents, int n){
  int i = blockIdx.x*256 + threadIdx.x;
  if (i >= n) return;
  int idx = loc[i];
  int c = idx >> 18;
  int rem = idx & 0x3FFFF;
  int row = rem >> 9, col = rem & 511;
  int bin = (c<<4) | (row >> 5);
  int lrow = row & 31;
  float v = vk[i]; v = v > 0.0f ? v : 0.0f;
  uint32_t slot = atomicAdd(&cnt[bin], 1u);
  if (slot < BCAP)
    ents[(size_t)bin*BCAP + slot] = ((uint32_t)((lrow<<9)|col) << 16) | f2bf(v);
}

// Pass 1k: SPARSE kernel-image row rfft. Same structure as k_p1 but the input
// rows are built by zeroing LDS and scattering the bin's ~195 entries.
__global__ __launch_bounds__(512) void k_p1k(const uint32_t* __restrict__ cnt,
                                             const uint32_t* __restrict__ ents,
                                             uint32_t* __restrict__ dst){
  __shared__ float sre[8][528], sim[8][528];
  __shared__ uint32_t staged[NU*33];
  const int tid = threadIdx.x;
  const int w = tid >> 6, t = tid & 63;
  const int img = blockIdx.x >> 4;             // channel
  const int rbi = blockIdx.x & 15;
  const int rblock = rbi << 5;                 // 32 rows per WG
  const int bin = (img<<4) | rbi;
  const int n_e = (int)min(cnt[bin], (uint32_t)BCAP);
  const uint32_t* eb = ents + (size_t)bin*BCAP;
  float t1r[8],t1i[8],t2r[8],t2i[8];
  make_tw(t, t1r,t1i,t2r,t2i);
  float* S = sre[w];
  float* T = sim[w];
  #pragma unroll
  for (int p=0; p<2; p++){
    const int il = (w<<2) + (p<<1);
    // build rows il (->S) and il+1 (->T): zero, then scatter matching entries
    for (int d = t; d < 528; d += 64){ S[d]=0.0f; T[d]=0.0f; }
    WAIT_LGKM();
    for (int j = t; j < n_e; j += 64){
      uint32_t e = eb[j];
      int code = e >> 16;
      int lrow = code >> 9, col = code & 511;
      float val = bf2f(e & 0xFFFFu);
      int d = col + (col>>5);
      if (lrow == il)   S[d] = val;
      if (lrow == il+1) T[d] = val;
    }
    WAIT_LGKM();
    float ar[8], ai[8];
    #pragma unroll
    for (int j=0;j<8;j++){ int s2=t+(j<<6); s2+=(s2>>5); ar[j]=S[s2]; ai[j]=T[s2]; }
    WAIT_LGKM();
    fft512<-1>(ar,ai,S,T,t,t1r,t1i,t2r,t2i);
    // stage Z (natural order) for hermitian untangle
    #pragma unroll
    for (int k=0;k<8;k++){ int d = t+(k<<6); d += (d>>5); S[d]=ar[k]; T[d]=ai[k]; }
    WAIT_LGKM();
    #pragma unroll
    for (int k=0;k<5;k++){
      int u = t + (k<<6);
      if (u < NU){
        int e2 = (512 - u) & 511;
        int du = u + (u>>5), d2 = e2 + (e2>>5);
        float zur=S[du], zui=T[du];
        float zvr=S[d2], zvi=T[d2];
        float Ar=0.5f*(zur+zvr), Ai=0.5f*(zui-zvi);   // even row spectrum
        float Br=0.5f*(zui+zvi), Bi=0.5f*(zvr-zur);   // odd row spectrum
        staged[u*33 + il]     = packbf(Ar,Ai);
        staged[u*33 + il + 1] = packbf(Br,Bi);
      }
    }
    WAIT_LGKM();
  }
  __syncthreads();
  uint32_t* ob = dst + (size_t)img*IMG_CPLX;
  for (int e = tid; e < NU*32; e += 512){
    int u = e >> 5, il2 = e & 31;
    ob[(size_t)u*NXX + rblock + il2] = staged[u*33 + il2];
  }
}

// Pass 1: row rfft of fp32 x (two real rows per complex FFT), transposed bf16
// output [img][u][i]. 32 rows per WG (8 waves x 2 row-pairs).
__global__ __launch_bounds__(512) void k_p1(const float* __restrict__ src,
                                            uint32_t* __restrict__ dst){
  __shared__ float sre[8][528], sim[8][528];
  __shared__ uint32_t staged[NU*33];
  const int tid = threadIdx.x;
  const int w = tid >> 6, t = tid & 63;
  const int img = blockIdx.x >> 4;
  const int rblock = (blockIdx.x & 15) << 5;   // 32 rows per WG
  float t1r[8],t1i[8],t2r[8],t2i[8];
  make_tw(t, t1r,t1i,t2r,t2i);
  float* S = sre[w];
  float* T = sim[w];
  #pragma unroll
  for (int p=0; p<2; p++){
    const int il = (w<<2) + (p<<1);
    float ar[8], ai[8];
    const float* rowA = src + (size_t)img*PIX + (size_t)(rblock + il)*NYY;
    #pragma unroll
    for (int j=0;j<8;j++){ ar[j]=rowA[t+(j<<6)]; ai[j]=rowA[NYY + t + (j<<6)]; }
    fft512<-1>(ar,ai,S,T,t,t1r,t1i,t2r,t2i);
    // stage Z (natural order) for hermitian untangle
    #pragma unroll
    for (int k=0;k<8;k++){ int d = t+(k<<6); d += (d>>5); S[d]=ar[k]; T[d]=ai[k]; }
    WAIT_LGKM();
    #pragma unroll
    for (int k=0;k<5;k++){
      int u = t + (k<<6);
      if (u < NU){
        int e2 = (512 - u) & 511;
        int du = u + (u>>5), d2 = e2 + (e2>>5);
        float zur=S[du], zui=T[du];
        float zvr=S[d2], zvi=T[d2];
        float Ar=0.5f*(zur+zvr), Ai=0.5f*(zui-zvi);   // even row spectrum
        float Br=0.5f*(zui+zvi), Bi=0.5f*(zvr-zur);   // odd row spectrum
        staged[u*33 + il]     = packbf(Ar,Ai);
        staged[u*33 + il + 1] = packbf(Br,Bi);
      }
    }
    WAIT_LGKM();
  }
  __syncthreads();
  uint32_t* ob = dst + (size_t)img*IMG_CPLX;
  for (int e = tid; e < NU*32; e += 512){
    int u = e >> 5, il2 = e & 31;
    ob[(size_t)u*NXX + rblock + il2] = staged[u*33 + il2];
  }
}

// Pass 2 (kernel only): in-place column FFT per (c,u) -> Kf
__global__ __launch_bounds__(512) void k_p2k(uint32_t* __restrict__ rtk){
  __shared__ float sre[8][528], sim[8][528];
  const int w = threadIdx.x >> 6, t = threadIdx.x & 63;
  const int fid = blockIdx.x*8 + w;     // < 32*257 exactly
  const int c = fid / NU, u = fid % NU;
  float t1r[8],t1i[8],t2r[8],t2i[8];
  make_tw(t, t1r,t1i,t2r,t2i);
  uint32_t* col = rtk + (size_t)c*IMG_CPLX + (size_t)u*NXX;
  float ar[8], ai[8];
  #pragma unroll
  for (int j=0;j<8;j++){ uint32_t v = col[t+(j<<6)]; ar[j]=bf2f(v & 0xFFFFu); ai[j]=bf2f(v >> 16); }
  fft512<-1>(ar,ai,sre[w],sim[w],t,t1r,t1i,t2r,t2i);
  #pragma unroll
  for (int k=0;k<8;k++){ col[t+(k<<6)] = packbf(ar[k], ai[k]); }
}

// Pass 3: WG per (u, bl). 8 waves x 4 channels: col-FFT(x) + Xf*Kf accumulate;
// cross-wave reduce ALIASED into the FFT scratch (LDS 33.8 KB);
// wave 0 runs the inverse column FFT and stores y3 (bf16).
// NO reg-count bound (R9: a 40-VGPR cap = 310 MB spill traffic, 264 us).
// NO SW-pipelining (R12: +8 us), NO LDS twiddles (R11: +55 us).
__global__ __launch_bounds__(512) void k_p3(const uint32_t* __restrict__ rtx,
    const uint32_t* __restrict__ rtk, uint32_t* __restrict__ y3, int b0){
  __shared__ float sre[8][528], sim[8][528];
  const int tid = threadIdx.x;
  const int w = tid >> 6, t = tid & 63;
  const int u  = blockIdx.x >> 3;
  const int bl = blockIdx.x & 7;
  float t1r[8],t1i[8],t2r[8],t2i[8];
  make_tw(t, t1r,t1i,t2r,t2i);
  float accr[8], acci[8];
  #pragma unroll
  for (int k=0;k<8;k++){ accr[k]=0.0f; acci[k]=0.0f; }
  #pragma unroll
  for (int cc=0; cc<4; cc++){
    const int c = (w<<2) + cc;
    const uint32_t* xc = rtx + ((size_t)(bl*NCH + c))*IMG_CPLX + (size_t)u*NXX;
    const uint32_t* kc = rtk + (size_t)c*IMG_CPLX + (size_t)u*NXX;
    uint32_t xv[8];
    #pragma unroll
    for (int j=0;j<8;j++){ xv[j]=xc[t+(j<<6)]; }
    float ar[8], ai[8];
    #pragma unroll
    for (int j=0;j<8;j++){ ar[j]=bf2f(xv[j] & 0xFFFFu); ai[j]=bf2f(xv[j] >> 16); }
    fft512<-1>(ar,ai,sre[w],sim[w],t,t1r,t1i,t2r,t2i);
    // kv loads after the FFT: L2/L3-resident, out of the FFT's live window
    uint32_t kv[8];
    #pragma unroll
    for (int j=0;j<8;j++){ kv[j]=kc[t+(j<<6)]; }
    #pragma unroll
    for (int k=0;k<8;k++){
      float kr=bf2f(kv[k] & 0xFFFFu), ki=bf2f(kv[k] >> 16);
      accr[k] += ar[k]*kr - ai[k]*ki;
      acci[k] += ar[k]*ki + ai[k]*kr;
    }
  }
  // per-wave partials into OWN scratch slice, natural order (own FFT reads done)
  #pragma unroll
  for (int k=0;k<8;k++){ sre[w][t+(k<<6)] = accr[k]; sim[w][t+(k<<6)] = acci[k]; }
  __syncthreads();
  // column `tid` owned by thread `tid` only: read all 8 partials, write slot 0
  const float scl = 1.0f/262144.0f;   // both irfft2 normalizations folded here
  float sr=0.0f, si=0.0f;
  #pragma unroll
  for (int ww=0; ww<8; ww++){ sr += sre[ww][tid]; si += sim[ww][tid]; }
  sre[0][tid] = sr*scl; sim[0][tid] = si*scl;
  __syncthreads();
  if (w==0){
    float ar[8], ai[8];
    #pragma unroll
    for (int j=0;j<8;j++){ ar[j]=sre[0][t+(j<<6)]; ai[j]=sim[0][t+(j<<6)]; }
    // sre[0]/sim[0] dead now (loaded to regs); reuse as inverse-FFT scratch
    fft512<1>(ar,ai,sre[0],sim[0],t,t1r,t1i,t2r,t2i);
    uint32_t* yc = y3 + ((size_t)(b0+bl)*NU + u)*NXX;
    #pragma unroll
    for (int k=0;k<8;k++){ yc[t+(k<<6)] = packbf(ar[k], ai[k]); }
  }
}

// Pass 4: inverse row FFT (hermitian reconstruction, 2 real output rows per wave)
__global__ __launch_bounds__(512) void k_p4(const uint32_t* __restrict__ y3,
                                            float* __restrict__ out){
  __shared__ float sre[8][528], sim[8][528];
  __shared__ uint32_t sta[NU*17];
  const int tid = threadIdx.x, w = tid>>6, t = tid&63;
  const int b = blockIdx.x >> 5;
  const int i0 = (blockIdx.x & 31) << 4;    // 16 rows per WG
  const uint32_t* yb = y3 + (size_t)b*IMG_CPLX;
  for (int e = tid; e < NU*16; e += 512){
    int u = e >> 4, il = e & 15;
    sta[u*17 + il] = yb[(size_t)u*NXX + i0 + il];
  }
  __syncthreads();
  float t1r[8],t1i[8],t2r[8],t2i[8];
  make_tw(t, t1r,t1i,t2r,t2i);
  float ar[8], ai[8];
  #pragma unroll
  for (int j=0;j<8;j++){
    int e = t + (j<<6);
    if (e <= 256){
      uint32_t pa_ = sta[e*17 + 2*w], pb_ = sta[e*17 + 2*w + 1];
      float Ar=bf2f(pa_&0xFFFFu), Ai=bf2f(pa_>>16);
      float Br=bf2f(pb_&0xFFFFu), Bi=bf2f(pb_>>16);
      ar[j] = Ar - Bi; ai[j] = Ai + Br;              // Z = A + iB
    } else {
      int ep = 512 - e;
      uint32_t pa_ = sta[ep*17 + 2*w], pb_ = sta[ep*17 + 2*w + 1];
      float Ar=bf2f(pa_&0xFFFFu), Ai=bf2f(pa_>>16);
      float Br=bf2f(pb_&0xFFFFu), Bi=bf2f(pb_>>16);
      ar[j] = Ar + Bi; ai[j] = Br - Ai;              // Z = conj(A') + i conj(B')
    }
  }
  fft512<1>(ar,ai,sre[w],sim[w],t,t1r,t1i,t2r,t2i);
  float* ob = out + (size_t)b*PIX + (size_t)(i0 + 2*w)*NYY;
  #pragma unroll
  for (int k=0;k<8;k++){ int n = t+(k<<6); ob[n]=ar[k]; ob[NYY+n]=ai[k]; }
}

extern "C" void kernel_launch(void* const* d_in, const int* in_sizes, int n_in,
                              void* d_out, int out_size, void* d_ws, size_t ws_size,
                              hipStream_t stream) {
  const float* x  = (const float*)d_in[0];
  const float* vk = (const float*)d_in[2];
  const int*   loc= (const int*)d_in[3];
  float* out = (float*)d_out;
  char* ws = (char*)d_ws;
  const int n_loc = in_sizes[2];

  // ws layout: y3 (4.21 MB) | cnt @5MB (2 KB) | ents @5MB+4KB (1.57 MB) |
  //            rtk @8MB (16.8 MB) | rtx @8MB+16.8MB (134.7 MB)  => ~159.5 MB
  uint32_t* y3   = (uint32_t*)ws;
  uint32_t* cnt  = (uint32_t*)(ws + (5u<<20));
  uint32_t* ents = (uint32_t*)(ws + (5u<<20) + 4096);
  uint32_t* rtk  = (uint32_t*)(ws + (8u<<20));
  uint32_t* rtx  = rtk + (size_t)NCH*IMG_CPLX;

  hipMemsetAsync(cnt, 0, 512*sizeof(uint32_t), stream);
  k_bin<<<(n_loc+255)/256, 256, 0, stream>>>(vk, loc, cnt, ents, n_loc);
  k_p1k<<<NCH*16, 512, 0, stream>>>(cnt, ents, rtk);
  k_p2k<<<(NCH*NU)/8, 512, 0, stream>>>(rtk);
  k_p1<<<NB*NCH*16, 512, 0, stream>>>(x, rtx);
  k_p3<<<NU*8, 512, 0, stream>>>(rtx, rtk, y3, 0);
  k_p4<<<NB*32, 512, 0, stream>>>(y3, out);
}

// Round 14
// 182.536 us; speedup vs baseline: 1.1590x; 1.1590x over previous
//
#include <hip/hip_runtime.h>
#include <cstdint>

#define NXX 512
#define NYY 512
#define NCH 32
#define NB  8
#define NU  257              // NYY/2+1
#define IMG_CPLX (NU*NXX)    // 131584 complex per image, [u][i] i-contiguous
#define PIX (NXX*NYY)        // 262144

__device__ __forceinline__ uint32_t f2bf(float f){
  uint32_t u = __float_as_uint(f);
  return (u + 0x7FFFu + ((u >> 16) & 1u)) >> 16;   // RNE
}
__device__ __forceinline__ float bf2f(uint32_t h){ return __uint_as_float(h << 16); }
__device__ __forceinline__ uint32_t packbf(float re, float im){ return f2bf(re) | (f2bf(im) << 16); }

#define WAIT_LGKM() asm volatile("s_waitcnt lgkmcnt(0)" ::: "memory")

__device__ __forceinline__ void cmul(float& zr, float& zi, float wr, float wi){
  float r = zr*wr - zi*wi;
  zi = zr*wi + zi*wr;
  zr = r;
}

// 8-point DFT, DIR=-1 forward (e^{-i}), DIR=+1 inverse (unnormalized)
template<int DIR>
__device__ __forceinline__ void bfly8(float* xr, float* xi){
  const float S = 0.70710678118654752440f;
  float er0=xr[0]+xr[4], ei0=xi[0]+xi[4];
  float er1=xr[1]+xr[5], ei1=xi[1]+xi[5];
  float er2=xr[2]+xr[6], ei2=xi[2]+xi[6];
  float er3=xr[3]+xr[7], ei3=xi[3]+xi[7];
  float or0=xr[0]-xr[4], oi0=xi[0]-xi[4];
  float or1=xr[1]-xr[5], oi1=xi[1]-xi[5];
  float or2=xr[2]-xr[6], oi2=xi[2]-xi[6];
  float or3=xr[3]-xr[7], oi3=xi[3]-xi[7];
  float p0r=er0+er2, p0i=ei0+ei2;
  float p1r=er0-er2, p1i=ei0-ei2;
  float q0r=er1+er3, q0i=ei1+ei3;
  float q1r=er1-er3, q1i=ei1-ei3;
  float w4r, w4i;
  if (DIR<0){ w4r=q1i; w4i=-q1r; } else { w4r=-q1i; w4i=q1r; }
  xr[0]=p0r+q0r; xi[0]=p0i+q0i;
  xr[4]=p0r-q0r; xi[4]=p0i-q0i;
  xr[2]=p1r+w4r; xi[2]=p1i+w4i;
  xr[6]=p1r-w4r; xi[6]=p1i-w4i;
  float f1r,f1i,f2r,f2i,f3r,f3i;
  if (DIR<0){
    f1r=S*(or1+oi1); f1i=S*(oi1-or1);
    f2r=oi2;         f2i=-or2;
    f3r=S*(oi3-or3); f3i=-S*(or3+oi3);
  } else {
    f1r=S*(or1-oi1);  f1i=S*(or1+oi1);
    f2r=-oi2;         f2i=or2;
    f3r=-S*(or3+oi3); f3i=S*(or3-oi3);
  }
  float g0r=or0+f2r, g0i=oi0+f2i;
  float g1r=or0-f2r, g1i=oi0-f2i;
  float h0r=f1r+f3r, h0i=f1i+f3i;
  float h1r=f1r-f3r, h1i=f1i-f3i;
  float v4r, v4i;
  if (DIR<0){ v4r=h1i; v4i=-h1r; } else { v4r=-h1i; v4i=h1r; }
  xr[1]=g0r+h0r; xi[1]=g0i+h0i;
  xr[5]=g0r-h0r; xi[5]=g0i-h0i;
  xr[3]=g1r+v4r; xi[3]=g1i+v4i;
  xr[7]=g1r-v4r; xi[7]=g1i-v4i;
}

__device__ __forceinline__ void make_tw(int t, float* t1r, float* t1i, float* t2r, float* t2i){
  const float TP = 6.283185307179586476925f;
  float s, c;
  sincosf(-TP * (float)t * (1.0f/512.0f), &s, &c);
  t1r[0]=1.0f; t1i[0]=0.0f;
  #pragma unroll
  for (int k=1;k<8;k++){ t1r[k]=t1r[k-1]*c - t1i[k-1]*s; t1i[k]=t1r[k-1]*s + t1i[k-1]*c; }
  sincosf(-TP * (float)(t>>3) * (1.0f/64.0f), &s, &c);
  t2r[0]=1.0f; t2i[0]=0.0f;
  #pragma unroll
  for (int k=1;k<8;k++){ t2r[k]=t2r[k-1]*c - t2i[k-1]*s; t2i[k]=t2r[k-1]*s + t2i[k-1]*c; }
}

// 512-pt complex Stockham radix-8, one wave, 8 complex/lane.
// Input : a[j] = x[t + 64j].  Output: a[k] = X[t + 64k] (natural order).
template<int DIR>
__device__ __forceinline__ void fft512(float* ar, float* ai, float* sre, float* sim, int t,
    const float* t1r, const float* t1i, const float* t2r, const float* t2i){
  bfly8<DIR>(ar, ai);
  #pragma unroll
  for (int k=1;k<8;k++){ cmul(ar[k], ai[k], t1r[k], (DIR<0)? t1i[k] : -t1i[k]); }
  #pragma unroll
  for (int k=0;k<8;k++){ int d = 8*t + k; d += (d>>5); sre[d]=ar[k]; sim[d]=ai[k]; }
  WAIT_LGKM();
  #pragma unroll
  for (int j=0;j<8;j++){ int s2 = t + (j<<6); s2 += (s2>>5); ar[j]=sre[s2]; ai[j]=sim[s2]; }
  WAIT_LGKM();
  bfly8<DIR>(ar, ai);
  #pragma unroll
  for (int k=1;k<8;k++){ cmul(ar[k], ai[k], t2r[k], (DIR<0)? t2i[k] : -t2i[k]); }
  #pragma unroll
  for (int k=0;k<8;k++){ int d = (t&7) + ((t>>3)<<6) + (k<<3); d += (d>>5); sre[d]=ar[k]; sim[d]=ai[k]; }
  WAIT_LGKM();
  #pragma unroll
  for (int j=0;j<8;j++){ int s2 = t + (j<<6); s2 += (s2>>5); ar[j]=sre[s2]; ai[j]=sim[s2]; }
  WAIT_LGKM();
  bfly8<DIR>(ar, ai);
}

__global__ __launch_bounds__(256) void k_zero(uint4* __restrict__ p, int n4){
  int stride = gridDim.x * 256;
  for (int i = blockIdx.x*256 + threadIdx.x; i < n4; i += stride)
    p[i] = make_uint4(0u,0u,0u,0u);
}

// scatter relu(vk) into zeroed bf16 kernel volume
__global__ void k_scatter(const float* __restrict__ vk, const int* __restrict__ loc,
                          uint16_t* __restrict__ kbuf, int n){
  int i = blockIdx.x*256 + threadIdx.x;
  if (i < n){ float v = vk[i]; v = v > 0.0f ? v : 0.0f; kbuf[loc[i]] = (uint16_t)f2bf(v); }
}

// Pass 1: row rfft (two real rows per complex FFT), transposed bf16 output [img][u][i].
// 32 rows per WG (8 waves x 2 row-pairs).
template<int BF16>
__global__ __launch_bounds__(512) void k_p1(const void* __restrict__ srcv,
                                            uint32_t* __restrict__ dst){
  __shared__ float sre[8][528], sim[8][528];
  __shared__ uint32_t staged[NU*33];
  const int tid = threadIdx.x;
  const int w = tid >> 6, t = tid & 63;
  const int img = blockIdx.x >> 4;
  const int rblock = (blockIdx.x & 15) << 5;   // 32 rows per WG
  float t1r[8],t1i[8],t2r[8],t2i[8];
  make_tw(t, t1r,t1i,t2r,t2i);
  float* S = sre[w];
  float* T = sim[w];
  #pragma unroll
  for (int p=0; p<2; p++){
    const int il = (w<<2) + (p<<1);
    float ar[8], ai[8];
    if (BF16){
      const uint16_t* base = (const uint16_t*)srcv + (size_t)img*PIX + (size_t)(rblock + il)*NYY;
      const uint4* A4 = (const uint4*)base;      // 64 uint4 per 512-elem row
      uint4 a = A4[t], b = A4[64+t];             // row il / row il+1
      uint32_t wa[4]={a.x,a.y,a.z,a.w}, wb[4]={b.x,b.y,b.z,b.w};
      #pragma unroll
      for (int q=0;q<4;q++){
        int e0=8*t+2*q, e1=e0+1;
        int d0=e0+(e0>>5), d1=e1+(e1>>5);
        S[d0]=bf2f(wa[q]&0xFFFFu); S[d1]=bf2f(wa[q]>>16);
        T[d0]=bf2f(wb[q]&0xFFFFu); T[d1]=bf2f(wb[q]>>16);
      }
      WAIT_LGKM();
      #pragma unroll
      for (int j=0;j<8;j++){ int s2=t+(j<<6); s2+=(s2>>5); ar[j]=S[s2]; ai[j]=T[s2]; }
      WAIT_LGKM();
    } else {
      const float* rowA = (const float*)srcv + (size_t)img*PIX + (size_t)(rblock + il)*NYY;
      #pragma unroll
      for (int j=0;j<8;j++){ ar[j]=rowA[t+(j<<6)]; ai[j]=rowA[NYY + t + (j<<6)]; }
    }
    fft512<-1>(ar,ai,S,T,t,t1r,t1i,t2r,t2i);
    // stage Z (natural order) for hermitian untangle
    #pragma unroll
    for (int k=0;k<8;k++){ int d = t+(k<<6); d += (d>>5); S[d]=ar[k]; T[d]=ai[k]; }
    WAIT_LGKM();
    #pragma unroll
    for (int k=0;k<5;k++){
      int u = t + (k<<6);
      if (u < NU){
        int e2 = (512 - u) & 511;
        int du = u + (u>>5), d2 = e2 + (e2>>5);
        float zur=S[du], zui=T[du];
        float zvr=S[d2], zvi=T[d2];
        float Ar=0.5f*(zur+zvr), Ai=0.5f*(zui-zvi);   // even row spectrum
        float Br=0.5f*(zui+zvi), Bi=0.5f*(zvr-zur);   // odd row spectrum
        staged[u*33 + il]     = packbf(Ar,Ai);
        staged[u*33 + il + 1] = packbf(Br,Bi);
      }
    }
    WAIT_LGKM();
  }
  __syncthreads();
  uint32_t* ob = dst + (size_t)img*IMG_CPLX;
  for (int e = tid; e < NU*32; e += 512){
    int u = e >> 5, il2 = e & 31;
    ob[(size_t)u*NXX + rblock + il2] = staged[u*33 + il2];
  }
}

// Pass 2 (kernel only): in-place column FFT per (c,u) -> Kf
__global__ __launch_bounds__(512) void k_p2k(uint32_t* __restrict__ rtk){
  __shared__ float sre[8][528], sim[8][528];
  const int w = threadIdx.x >> 6, t = threadIdx.x & 63;
  const int fid = blockIdx.x*8 + w;     // < 32*257 exactly
  const int c = fid / NU, u = fid % NU;
  float t1r[8],t1i[8],t2r[8],t2i[8];
  make_tw(t, t1r,t1i,t2r,t2i);
  uint32_t* col = rtk + (size_t)c*IMG_CPLX + (size_t)u*NXX;
  float ar[8], ai[8];
  #pragma unroll
  for (int j=0;j<8;j++){ uint32_t v = col[t+(j<<6)]; ar[j]=bf2f(v & 0xFFFFu); ai[j]=bf2f(v >> 16); }
  fft512<-1>(ar,ai,sre[w],sim[w],t,t1r,t1i,t2r,t2i);
  #pragma unroll
  for (int k=0;k<8;k++){ col[t+(k<<6)] = packbf(ar[k], ai[k]); }
}

// Pass 3: WG per (u, bl). 8 waves x 4 channels: col-FFT(x) + Xf*Kf accumulate;
// cross-wave reduce ALIASED into the FFT scratch (LDS 33.8 KB);
// wave 0 runs the inverse column FFT and stores y3 (bf16).
// NO reg-count bound (R9: a 40-VGPR cap = 310 MB spill traffic, 264 us).
// NO SW-pipelining (R12: +8 us), NO LDS twiddles (R11: +55 us).
__global__ __launch_bounds__(512) void k_p3(const uint32_t* __restrict__ rtx,
    const uint32_t* __restrict__ rtk, uint32_t* __restrict__ y3, int b0){
  __shared__ float sre[8][528], sim[8][528];
  const int tid = threadIdx.x;
  const int w = tid >> 6, t = tid & 63;
  const int u  = blockIdx.x >> 3;
  const int bl = blockIdx.x & 7;
  float t1r[8],t1i[8],t2r[8],t2i[8];
  make_tw(t, t1r,t1i,t2r,t2i);
  float accr[8], acci[8];
  #pragma unroll
  for (int k=0;k<8;k++){ accr[k]=0.0f; acci[k]=0.0f; }
  #pragma unroll
  for (int cc=0; cc<4; cc++){
    const int c = (w<<2) + cc;
    const uint32_t* xc = rtx + ((size_t)(bl*NCH + c))*IMG_CPLX + (size_t)u*NXX;
    const uint32_t* kc = rtk + (size_t)c*IMG_CPLX + (size_t)u*NXX;
    uint32_t xv[8];
    #pragma unroll
    for (int j=0;j<8;j++){ xv[j]=xc[t+(j<<6)]; }
    float ar[8], ai[8];
    #pragma unroll
    for (int j=0;j<8;j++){ ar[j]=bf2f(xv[j] & 0xFFFFu); ai[j]=bf2f(xv[j] >> 16); }
    fft512<-1>(ar,ai,sre[w],sim[w],t,t1r,t1i,t2r,t2i);
    // kv loads after the FFT: L2/L3-resident, out of the FFT's live window
    uint32_t kv[8];
    #pragma unroll
    for (int j=0;j<8;j++){ kv[j]=kc[t+(j<<6)]; }
    #pragma unroll
    for (int k=0;k<8;k++){
      float kr=bf2f(kv[k] & 0xFFFFu), ki=bf2f(kv[k] >> 16);
      accr[k] += ar[k]*kr - ai[k]*ki;
      acci[k] += ar[k]*ki + ai[k]*kr;
    }
  }
  // per-wave partials into OWN scratch slice, natural order (own FFT reads done)
  #pragma unroll
  for (int k=0;k<8;k++){ sre[w][t+(k<<6)] = accr[k]; sim[w][t+(k<<6)] = acci[k]; }
  __syncthreads();
  // column `tid` owned by thread `tid` only: read all 8 partials, write slot 0
  const float scl = 1.0f/262144.0f;   // both irfft2 normalizations folded here
  float sr=0.0f, si=0.0f;
  #pragma unroll
  for (int ww=0; ww<8; ww++){ sr += sre[ww][tid]; si += sim[ww][tid]; }
  sre[0][tid] = sr*scl; sim[0][tid] = si*scl;
  __syncthreads();
  if (w==0){
    float ar[8], ai[8];
    #pragma unroll
    for (int j=0;j<8;j++){ ar[j]=sre[0][t+(j<<6)]; ai[j]=sim[0][t+(j<<6)]; }
    // sre[0]/sim[0] dead now (loaded to regs); reuse as inverse-FFT scratch
    fft512<1>(ar,ai,sre[0],sim[0],t,t1r,t1i,t2r,t2i);
    uint32_t* yc = y3 + ((size_t)(b0+bl)*NU + u)*NXX;
    #pragma unroll
    for (int k=0;k<8;k++){ yc[t+(k<<6)] = packbf(ar[k], ai[k]); }
  }
}

// Pass 4: inverse row FFT (hermitian reconstruction, 2 real output rows per wave)
__global__ __launch_bounds__(512) void k_p4(const uint32_t* __restrict__ y3,
                                            float* __restrict__ out){
  __shared__ float sre[8][528], sim[8][528];
  __shared__ uint32_t sta[NU*17];
  const int tid = threadIdx.x, w = tid>>6, t = tid&63;
  const int b = blockIdx.x >> 5;
  const int i0 = (blockIdx.x & 31) << 4;    // 16 rows per WG
  const uint32_t* yb = y3 + (size_t)b*IMG_CPLX;
  for (int e = tid; e < NU*16; e += 512){
    int u = e >> 4, il = e & 15;
    sta[u*17 + il] = yb[(size_t)u*NXX + i0 + il];
  }
  __syncthreads();
  float t1r[8],t1i[8],t2r[8],t2i[8];
  make_tw(t, t1r,t1i,t2r,t2i);
  float ar[8], ai[8];
  #pragma unroll
  for (int j=0;j<8;j++){
    int e = t + (j<<6);
    if (e <= 256){
      uint32_t pa_ = sta[e*17 + 2*w], pb_ = sta[e*17 + 2*w + 1];
      float Ar=bf2f(pa_&0xFFFFu), Ai=bf2f(pa_>>16);
      float Br=bf2f(pb_&0xFFFFu), Bi=bf2f(pb_>>16);
      ar[j] = Ar - Bi; ai[j] = Ai + Br;              // Z = A + iB
    } else {
      int ep = 512 - e;
      uint32_t pa_ = sta[ep*17 + 2*w], pb_ = sta[ep*17 + 2*w + 1];
      float Ar=bf2f(pa_&0xFFFFu), Ai=bf2f(pa_>>16);
      float Br=bf2f(pb_&0xFFFFu), Bi=bf2f(pb_>>16);
      ar[j] = Ar + Bi; ai[j] = Br - Ai;              // Z = conj(A') + i conj(B')
    }
  }
  fft512<1>(ar,ai,sre[w],sim[w],t,t1r,t1i,t2r,t2i);
  float* ob = out + (size_t)b*PIX + (size_t)(i0 + 2*w)*NYY;
  #pragma unroll
  for (int k=0;k<8;k++){ int n = t+(k<<6); ob[n]=ar[k]; ob[NYY+n]=ai[k]; }
}

extern "C" void kernel_launch(void* const* d_in, const int* in_sizes, int n_in,
                              void* d_out, int out_size, void* d_ws, size_t ws_size,
                              hipStream_t stream) {
  const float* x  = (const float*)d_in[0];
  const float* vk = (const float*)d_in[2];
  const int*   loc= (const int*)d_in[3];
  float* out = (float*)d_out;
  char* ws = (char*)d_ws;
  const int n_loc = in_sizes[2];

  const size_t kbytes16 = (size_t)NCH*PIX*2;       // 16.7 MiB bf16 kernel volume

  uint16_t* kbuf = (uint16_t*)ws;
  uint32_t* y3   = (uint32_t*)ws;                  // alias: kbuf dead after p1<1> (4.2 MB)
  uint32_t* rtk  = (uint32_t*)(ws + kbytes16);
  uint32_t* rtx  = rtk + (size_t)NCH*IMG_CPLX;
  // total: 16.7M + 16.8M + 134.7M ≈ 168.2 MB

  k_zero<<<2048, 256, 0, stream>>>((uint4*)kbuf, (int)(kbytes16/16));
  k_scatter<<<(n_loc+255)/256, 256, 0, stream>>>(vk, loc, kbuf, n_loc);
  k_p1<1><<<NCH*16, 512, 0, stream>>>(kbuf, rtk);
  k_p2k<<<(NCH*NU)/8, 512, 0, stream>>>(rtk);
  k_p1<0><<<NB*NCH*16, 512, 0, stream>>>(x, rtx);
  k_p3<<<NU*8, 512, 0, stream>>>(rtx, rtk, y3, 0);
  k_p4<<<NB*32, 512, 0, stream>>>(y3, out);
}